// Round 5
// baseline (239.830 us; speedup 1.0000x reference)
//
#include <hip/hip_runtime.h>
#include <hip/hip_bf16.h>
#include <math.h>

typedef unsigned short u16;
typedef __attribute__((ext_vector_type(8))) short short8;
typedef __attribute__((ext_vector_type(4))) float floatx4;

constexpr int kN   = 1024;
constexpr int kB   = 256;
constexpr int kE   = 8192;
constexpr int kHD  = 20;
constexpr float kEps = 1e-5f;

static __device__ __forceinline__ float u16_bf16_to_f32(u16 v) {
  return __uint_as_float(((unsigned)v) << 16);
}
static __device__ __forceinline__ void unpack2(unsigned u, float& a, float& b) {
  a = __uint_as_float(u << 16);
  b = __uint_as_float(u & 0xffff0000u);
}
static __device__ __forceinline__ u16 f2bf(float f) {
  __hip_bfloat16 h = __float2bfloat16(f);
  return *reinterpret_cast<u16*>(&h);
}
static __device__ __forceinline__ unsigned pack_bf16(float a, float b) {
  return (unsigned)f2bf(a) | ((unsigned)f2bf(b) << 16);
}

// per-block dtype detect (bf16 vs fp32) from first 64 words of x; no cross-block dep
static __device__ __forceinline__ int detect_flag(const unsigned* __restrict__ x) {
  __shared__ int sflag;
  int t = threadIdx.x;
  if (t < 64) {
    unsigned w = x[t];
    unsigned e = (w >> 7) & 0xFFu;
    unsigned long long bl = __ballot(e >= 114u && e <= 136u);
    if (t == 0) sflag = (__popcll(bl) >= 32) ? 1 : 0;
  }
  __syncthreads();
  return sflag;
}

// ---------------- prep: csr + small convs + repack + x transpose + zero sums ----------------
struct SmallConv {
  const void* src[17];
  float* dst[17];
  int n[17];
};

struct PrepArgs {
  const unsigned* x;
  const int* ei;
  const void* W1; const void* W2; const void* Wout;
  SmallConv sc;
  float* x_f;
  u16* W1p; u16* W2p; u16* Woutp;
  int* csr_off; int* csr_src;
  float* sums;   // 640 floats zeroed (sums0+sums1)
};

// W repack into MFMA B-fragment cells: cell c=(kb*4+q)*N+n holds W[kb*32+q*8+j][n], j=0..7
static __device__ __forceinline__ void repack_one(const void* src, u16* dst, int c, int N, int srcbf) {
  int n = c % N;
  int t2 = c / N;
  int q = t2 & 3, kb = t2 >> 2;
  int k0 = kb * 32 + q * 8;
  u16 w[8];
  if (srcbf) {
    const u16* s = (const u16*)src;
#pragma unroll
    for (int j = 0; j < 8; j++) w[j] = s[(size_t)(k0 + j) * N + n];
  } else {
    const float* s = (const float*)src;
#pragma unroll
    for (int j = 0; j < 8; j++) w[j] = f2bf(s[(size_t)(k0 + j) * N + n]);
  }
  uint4 out;
  out.x = (unsigned)w[0] | ((unsigned)w[1] << 16);
  out.y = (unsigned)w[2] | ((unsigned)w[3] << 16);
  out.z = (unsigned)w[4] | ((unsigned)w[5] << 16);
  out.w = (unsigned)w[6] | ((unsigned)w[7] << 16);
  *((uint4*)(dst + (size_t)c * 8)) = out;
}

__global__ __launch_bounds__(256) void prep_kernel(PrepArgs pa) {
  int bid = blockIdx.x;
  int t = threadIdx.x;
  if (bid == 0) {
    // ---- CSR build with 256 threads ----
    __shared__ int cnt[kN];
    __shared__ int cur[kN];
    __shared__ int wsum[4];
    for (int i = t; i < kN; i += 256) cnt[i] = 0;
    __syncthreads();
    for (int e = t; e < kE; e += 256) atomicAdd(&cnt[pa.ei[kE + e]], 1);
    __syncthreads();
    int d[4], pre[4];
    int s = 0;
#pragma unroll
    for (int j = 0; j < 4; j++) { d[j] = cnt[t * 4 + j] + 1; pre[j] = s; s += d[j]; }
    int lane = t & 63;
    int v = s;
    for (int o = 1; o < 64; o <<= 1) { int u = __shfl_up(v, o); if (lane >= o) v += u; }
    if (lane == 63) wsum[t >> 6] = v;
    __syncthreads();
    int wbase = 0;
    for (int w = 0; w < (t >> 6); w++) wbase += wsum[w];
    int base = wbase + v - s;
#pragma unroll
    for (int j = 0; j < 4; j++) {
      pa.csr_off[t * 4 + j] = base + pre[j];
      cur[t * 4 + j] = base + pre[j];
    }
    if (t == 255) pa.csr_off[kN] = wbase + v;
    __syncthreads();
    for (int e = t; e < kE; e += 256) {
      int sv = pa.ei[e], dv = pa.ei[kE + e];
      int pos = atomicAdd(&cur[dv], 1);
      pa.csr_src[pos] = sv;
    }
    for (int i = t; i < kN; i += 256) {   // self loops
      int pos = atomicAdd(&cur[i], 1);
      pa.csr_src[pos] = i;
    }
    return;
  }
  int flag = detect_flag(pa.x);
  if (bid == 1) {
    // ---- zero sums + small fp32 convs ----
    for (int i = t; i < 640; i += 256) pa.sums[i] = 0.f;
    for (int k = 0; k < 17; k++) {
      int n = pa.sc.n[k];
      float* d = pa.sc.dst[k];
      if (flag) {
        const u16* s = (const u16*)pa.sc.src[k];
        for (int i = t; i < n; i += 256) d[i] = u16_bf16_to_f32(s[i]);
      } else {
        const float* s = (const float*)pa.sc.src[k];
        for (int i = t; i < n; i += 256) d[i] = s[i];
      }
    }
    return;
  }
  if (bid < 158) {
    // ---- repack W1 (34816 cells), W2 (4096), Wout (1024) ----
    int c = (bid - 2) * 256 + t;
    if (c < 34816) repack_one(pa.W1, pa.W1p, c, 256, flag);
    else if (c < 34816 + 4096) repack_one(pa.W2, pa.W2p, c - 34816, 128, flag);
    else if (c < 34816 + 4096 + 1024) repack_one(pa.Wout, pa.Woutp, c - 34816 - 4096, 64, flag);
    return;
  }
  // ---- x [B,N,8] -> x_f [N,B,8] fp32 (coalesced reads) ----
  int rid = (bid - 158) * 256 + t;  // = b*1024+n
  int b = rid >> 10, n = rid & 1023;
  float v[8];
  if (flag) {
    uint4 r = *((const uint4*)((const u16*)pa.x + (size_t)rid * 8));
    unpack2(r.x, v[0], v[1]); unpack2(r.y, v[2], v[3]);
    unpack2(r.z, v[4], v[5]); unpack2(r.w, v[6], v[7]);
  } else {
    const float4* s = (const float4*)((const float*)pa.x + (size_t)rid * 8);
    float4 r0 = s[0], r1 = s[1];
    v[0] = r0.x; v[1] = r0.y; v[2] = r0.z; v[3] = r0.w;
    v[4] = r1.x; v[5] = r1.y; v[6] = r1.z; v[7] = r1.w;
  }
  float* d = pa.x_f + ((size_t)n * kB + b) * 8;
  ((float4*)d)[0] = make_float4(v[0], v[1], v[2], v[3]);
  ((float4*)d)[1] = make_float4(v[4], v[5], v[6], v[7]);
}

// ---------------- layer 0 left-linear: x_f[N,B,8] -> xl [N,B,20] bf16 ----------------
__global__ __launch_bounds__(256) void lin0_kernel(const float* __restrict__ x_f,
                                                   const float* __restrict__ Wl,
                                                   u16* __restrict__ xlb) {
  __shared__ float wl[160];
  int t = threadIdx.x;
  if (t < 160) wl[t] = Wl[t];
  __syncthreads();
  int n = blockIdx.x, b = t;
  const float4* xp = (const float4*)(x_f + ((size_t)n * kB + b) * 8);
  float xi[8];
  {
    float4 v0 = xp[0], v1 = xp[1];
    xi[0] = v0.x; xi[1] = v0.y; xi[2] = v0.z; xi[3] = v0.w;
    xi[4] = v1.x; xi[5] = v1.y; xi[6] = v1.z; xi[7] = v1.w;
  }
  float ol[kHD];
#pragma unroll
  for (int f = 0; f < kHD; f++) {
    float al = 0.f;
#pragma unroll
    for (int i = 0; i < 8; i++) al = fmaf(xi[i], wl[i * kHD + f], al);
    ol[f] = al;
  }
  uint2* pl = (uint2*)(xlb + ((size_t)n * kB + b) * kHD);
#pragma unroll
  for (int k = 0; k < 5; k++)
    pl[k] = make_uint2(pack_bf16(ol[4 * k], ol[4 * k + 1]), pack_bf16(ol[4 * k + 2], ol[4 * k + 3]));
}

// ---------------- layer 1 left-linear (BN0 fold inlined): hb -> xl bf16 ----------------
__global__ __launch_bounds__(256) void lin1_kernel(const u16* __restrict__ hb,
                                                   const float* __restrict__ sums0,
                                                   const float* __restrict__ g0,
                                                   const float* __restrict__ be0,
                                                   const float* __restrict__ Wl1,
                                                   u16* __restrict__ xlb) {
  __shared__ float wl[400], sbl[kHD], afold[kHD], cfold[kHD], tot[2 * kHD];
  int t = threadIdx.x;
  if (t < 2 * kHD) {
    float v = 0.f;
    for (int k = 0; k < 8; k++) v += sums0[k * 2 * kHD + t];
    tot[t] = v;
  }
  __syncthreads();
  if (t < kHD) {
    const float inv = 1.0f / (float)(kN * kB);
    float mu = tot[t] * inv;
    float var = tot[kHD + t] * inv - mu * mu;
    float a = g0[t] * rsqrtf(var + kEps);
    afold[t] = a;
    cfold[t] = be0[t] - mu * a;
  }
  __syncthreads();
  for (int idx = t; idx < 400; idx += 256) wl[idx] = afold[idx / kHD] * Wl1[idx];
  if (t < kHD) {
    float s = 0.f;
    for (int f = 0; f < kHD; f++) s += cfold[f] * Wl1[f * kHD + t];
    sbl[t] = s;
  }
  __syncthreads();
  int n = blockIdx.x, b = t;
  float hv[kHD];
  {
    const uint2* p = (const uint2*)(hb + ((size_t)n * kB + b) * kHD);
#pragma unroll
    for (int k = 0; k < 5; k++) {
      uint2 v = p[k];
      unpack2(v.x, hv[4 * k], hv[4 * k + 1]);
      unpack2(v.y, hv[4 * k + 2], hv[4 * k + 3]);
    }
  }
  float ol[kHD];
#pragma unroll
  for (int j = 0; j < kHD; j++) {
    float al = sbl[j];
#pragma unroll
    for (int f = 0; f < kHD; f++) al = fmaf(hv[f], wl[f * kHD + j], al);
    ol[j] = al;
  }
  uint2* pl = (uint2*)(xlb + ((size_t)n * kB + b) * kHD);
#pragma unroll
  for (int k = 0; k < 5; k++)
    pl[k] = make_uint2(pack_bf16(ol[4 * k], ol[4 * k + 1]), pack_bf16(ol[4 * k + 2], ol[4 * k + 3]));
}

// ---------------- attention core (shared by both layers) ----------------
// caller provides xrv[20]; gathers xl[src] rows with depth-2 pipeline; writes h + stats
static __device__ __forceinline__ void attn_core(const u16* __restrict__ xlb,
                                                 const int* __restrict__ csr_src,
                                                 const int* __restrict__ ssrc,
                                                 int beg, int deg, int b,
                                                 const float* satt, const float* sbias,
                                                 float (&red)[2][2 * kHD],
                                                 int n, int bsw,
                                                 u16* __restrict__ hout,
                                                 float* __restrict__ sums) {
  float xrv[kHD];
  // xrv passed via satt? no — computed by caller into registers; this helper reads from caller
  (void)xrv;
}

__global__ __launch_bounds__(128) void attn0_kernel(const u16* __restrict__ xlb,
                                                    const float* __restrict__ x_f,
                                                    const float* __restrict__ Wr0,
                                                    const float* __restrict__ att,
                                                    const float* __restrict__ bias,
                                                    const int* __restrict__ csr_off,
                                                    const int* __restrict__ csr_src,
                                                    u16* __restrict__ hout,
                                                    float* __restrict__ sums) {
  __shared__ float satt[kHD], sbias[kHD], swr[160];
  __shared__ float red[2][2 * kHD];
  __shared__ int ssrc[128];
  int t = threadIdx.x;
  if (t < kHD) { satt[t] = att[t]; sbias[t] = bias[t]; }
  for (int i = t; i < 160; i += 128) swr[i] = Wr0[i];
  int n = blockIdx.x >> 1;
  int beg = csr_off[n], end = csr_off[n + 1];
  int deg = end - beg;
  for (int i = t; i < deg && i < 128; i += 128) ssrc[i] = csr_src[beg + i];
  __syncthreads();
  int b = ((blockIdx.x & 1) << 7) | t;
  // xr inline: x_f[n][b][:] @ Wr0
  float xrv[kHD];
  {
    const float4* xp = (const float4*)(x_f + ((size_t)n * kB + b) * 8);
    float4 v0 = xp[0], v1 = xp[1];
    float xi[8] = {v0.x, v0.y, v0.z, v0.w, v1.x, v1.y, v1.z, v1.w};
#pragma unroll
    for (int f = 0; f < kHD; f++) {
      float a = 0.f;
#pragma unroll
      for (int i = 0; i < 8; i++) a = fmaf(xi[i], swr[i * kHD + f], a);
      xrv[f] = a;
    }
  }
  float s[4] = {0.f, 0.f, 0.f, 0.f};
  float acc[kHD];
#pragma unroll
  for (int f = 0; f < kHD; f++) acc[f] = 0.f;

  auto loadrow = [&](int i, uint2 (&rr)[5]) {
    int srcn = (i < 128) ? ssrc[i] : csr_src[beg + i];
    const uint2* p = (const uint2*)(xlb + ((size_t)srcn * kB + b) * kHD);
#pragma unroll
    for (int k = 0; k < 5; k++) rr[k] = p[k];
  };
  auto consume = [&](uint2 (&rr)[5]) {
    float xs[kHD];
#pragma unroll
    for (int k = 0; k < 5; k++) {
      unpack2(rr[k].x, xs[4 * k], xs[4 * k + 1]);
      unpack2(rr[k].y, xs[4 * k + 2], xs[4 * k + 3]);
    }
#pragma unroll
    for (int hh = 0; hh < 4; hh++) {
      float e = 0.f;
#pragma unroll
      for (int d2 = 0; d2 < 5; d2++) {
        int f = hh * 5 + d2;
        float v = xs[f] + xrv[f];
        v = fmaxf(v, 0.2f * v);
        e = fmaf(v, satt[f], e);
      }
      float p = __expf(e);
      s[hh] += p;
#pragma unroll
      for (int d2 = 0; d2 < 5; d2++) {
        int f = hh * 5 + d2;
        acc[f] = fmaf(p, xs[f], acc[f]);
      }
    }
  };

  uint2 r0[5], r1[5];
  loadrow(0, r0);
  if (deg > 1) loadrow(1, r1);
  int i = 0;
  for (; i + 1 < deg; i += 2) {
    consume(r0);
    if (i + 2 < deg) loadrow(i + 2, r0);
    consume(r1);
    if (i + 3 < deg) loadrow(i + 3, r1);
  }
  if (i < deg) consume(r0);

  float hv[kHD];
#pragma unroll
  for (int hh = 0; hh < 4; hh++) {
    float inv = 1.f / s[hh];
#pragma unroll
    for (int d2 = 0; d2 < 5; d2++) {
      int f = hh * 5 + d2;
      hv[f] = fmaf(acc[f], inv, sbias[f]);
    }
  }
  {
    uint2* ph = (uint2*)(hout + ((size_t)n * kB + b) * kHD);
#pragma unroll
    for (int k = 0; k < 5; k++)
      ph[k] = make_uint2(pack_bf16(hv[4 * k], hv[4 * k + 1]), pack_bf16(hv[4 * k + 2], hv[4 * k + 3]));
  }
  int lane = t & 63, wv = t >> 6;
#pragma unroll
  for (int f = 0; f < kHD; f++) {
    float a = hv[f], q = hv[f] * hv[f];
    for (int o = 32; o > 0; o >>= 1) { a += __shfl_down(a, o); q += __shfl_down(q, o); }
    if (lane == 0) { red[wv][f] = a; red[wv][kHD + f] = q; }
  }
  __syncthreads();
  if (t < 2 * kHD) atomicAdd(&sums[(blockIdx.x & 7) * 2 * kHD + t], red[0][t] + red[1][t]);
}

__global__ __launch_bounds__(128) void attn1_kernel(const u16* __restrict__ xlb,
                                                    const u16* __restrict__ hb,
                                                    const float* __restrict__ sums0,
                                                    const float* __restrict__ g0,
                                                    const float* __restrict__ be0,
                                                    const float* __restrict__ Wr1,
                                                    const float* __restrict__ att,
                                                    const float* __restrict__ bias,
                                                    const int* __restrict__ csr_off,
                                                    const int* __restrict__ csr_src,
                                                    u16* __restrict__ hout,
                                                    float* __restrict__ sums) {
  __shared__ float satt[kHD], sbias[kHD], swr[400], sbr[kHD];
  __shared__ float afold[kHD], cfold[kHD], tot[2 * kHD];
  __shared__ float red[2][2 * kHD];
  __shared__ int ssrc[128];
  int t = threadIdx.x;
  if (t < kHD) { satt[t] = att[t]; sbias[t] = bias[t]; }
  if (t >= 64 && t < 64 + 2 * kHD) {
    int j = t - 64;
    float v = 0.f;
    for (int k = 0; k < 8; k++) v += sums0[k * 2 * kHD + j];
    tot[j] = v;
  }
  int n = blockIdx.x >> 1;
  int beg = csr_off[n], end = csr_off[n + 1];
  int deg = end - beg;
  for (int i = t; i < deg && i < 128; i += 128) ssrc[i] = csr_src[beg + i];
  __syncthreads();
  if (t < kHD) {
    const float inv = 1.0f / (float)(kN * kB);
    float mu = tot[t] * inv;
    float var = tot[kHD + t] * inv - mu * mu;
    float a = g0[t] * rsqrtf(var + kEps);
    afold[t] = a;
    cfold[t] = be0[t] - mu * a;
  }
  __syncthreads();
  for (int idx = t; idx < 400; idx += 128) swr[idx] = afold[idx / kHD] * Wr1[idx];
  if (t < kHD) {
    float sv = 0.f;
    for (int f = 0; f < kHD; f++) sv = fmaf(cfold[f], Wr1[f * kHD + t], sv);
    sbr[t] = sv;
  }
  __syncthreads();
  int b = ((blockIdx.x & 1) << 7) | t;
  // xr inline: BN0-folded h @ Wr1
  float xrv[kHD];
  {
    float hv0[kHD];
    const uint2* p = (const uint2*)(hb + ((size_t)n * kB + b) * kHD);
#pragma unroll
    for (int k = 0; k < 5; k++) {
      uint2 v = p[k];
      unpack2(v.x, hv0[4 * k], hv0[4 * k + 1]);
      unpack2(v.y, hv0[4 * k + 2], hv0[4 * k + 3]);
    }
#pragma unroll
    for (int j = 0; j < kHD; j++) {
      float a = sbr[j];
#pragma unroll
      for (int f = 0; f < kHD; f++) a = fmaf(hv0[f], swr[f * kHD + j], a);
      xrv[j] = a;
    }
  }
  float s[4] = {0.f, 0.f, 0.f, 0.f};
  float acc[kHD];
#pragma unroll
  for (int f = 0; f < kHD; f++) acc[f] = 0.f;

  auto loadrow = [&](int i, uint2 (&rr)[5]) {
    int srcn = (i < 128) ? ssrc[i] : csr_src[beg + i];
    const uint2* p = (const uint2*)(xlb + ((size_t)srcn * kB + b) * kHD);
#pragma unroll
    for (int k = 0; k < 5; k++) rr[k] = p[k];
  };
  auto consume = [&](uint2 (&rr)[5]) {
    float xs[kHD];
#pragma unroll
    for (int k = 0; k < 5; k++) {
      unpack2(rr[k].x, xs[4 * k], xs[4 * k + 1]);
      unpack2(rr[k].y, xs[4 * k + 2], xs[4 * k + 3]);
    }
#pragma unroll
    for (int hh = 0; hh < 4; hh++) {
      float e = 0.f;
#pragma unroll
      for (int d2 = 0; d2 < 5; d2++) {
        int f = hh * 5 + d2;
        float v = xs[f] + xrv[f];
        v = fmaxf(v, 0.2f * v);
        e = fmaf(v, satt[f], e);
      }
      float p = __expf(e);
      s[hh] += p;
#pragma unroll
      for (int d2 = 0; d2 < 5; d2++) {
        int f = hh * 5 + d2;
        acc[f] = fmaf(p, xs[f], acc[f]);
      }
    }
  };

  uint2 r0[5], r1[5];
  loadrow(0, r0);
  if (deg > 1) loadrow(1, r1);
  int i = 0;
  for (; i + 1 < deg; i += 2) {
    consume(r0);
    if (i + 2 < deg) loadrow(i + 2, r0);
    consume(r1);
    if (i + 3 < deg) loadrow(i + 3, r1);
  }
  if (i < deg) consume(r0);

  float hv[kHD];
#pragma unroll
  for (int hh = 0; hh < 4; hh++) {
    float inv = 1.f / s[hh];
#pragma unroll
    for (int d2 = 0; d2 < 5; d2++) {
      int f = hh * 5 + d2;
      hv[f] = fmaf(acc[f], inv, sbias[f]);
    }
  }
  {
    uint2* ph = (uint2*)(hout + ((size_t)n * kB + b) * kHD);
#pragma unroll
    for (int k = 0; k < 5; k++)
      ph[k] = make_uint2(pack_bf16(hv[4 * k], hv[4 * k + 1]), pack_bf16(hv[4 * k + 2], hv[4 * k + 3]));
  }
  int lane = t & 63, wv = t >> 6;
#pragma unroll
  for (int f = 0; f < kHD; f++) {
    float a = hv[f], q = hv[f] * hv[f];
    for (int o = 32; o > 0; o >>= 1) { a += __shfl_down(a, o); q += __shfl_down(q, o); }
    if (lane == 0) { red[wv][f] = a; red[wv][kHD + f] = q; }
  }
  __syncthreads();
  if (t < 2 * kHD) atomicAdd(&sums[(blockIdx.x & 7) * 2 * kHD + t], red[0][t] + red[1][t]);
}

// ---------------- pool + BN1 + agg + obs -> FIN[256,1088] bf16 ----------------
__global__ __launch_bounds__(256) void pool_fin_kernel(const u16* __restrict__ hb,
                                                       const float* __restrict__ sums,
                                                       const float* __restrict__ g1,
                                                       const float* __restrict__ be1,
                                                       const float* __restrict__ Wagg,
                                                       const float* __restrict__ bagg,
                                                       const void* __restrict__ obsraw,
                                                       const unsigned* __restrict__ xdet,
                                                       u16* __restrict__ finb) {
  int flag = detect_flag(xdet);
  int b = blockIdx.x, t = threadIdx.x;
  float acc[kHD];
#pragma unroll
  for (int f = 0; f < kHD; f++) acc[f] = 0.f;
  for (int n = t; n < kN; n += 256) {
    const uint2* p = (const uint2*)(hb + ((size_t)n * kB + b) * kHD);
#pragma unroll
    for (int k = 0; k < 5; k++) {
      uint2 v = p[k];
      float a0, a1, a2, a3;
      unpack2(v.x, a0, a1); unpack2(v.y, a2, a3);
      acc[4 * k] += a0; acc[4 * k + 1] += a1; acc[4 * k + 2] += a2; acc[4 * k + 3] += a3;
    }
  }
  __shared__ float red[4][kHD];
  __shared__ float tot[2 * kHD], pv[kHD];
#pragma unroll
  for (int f = 0; f < kHD; f++) {
    float v = acc[f];
    for (int o = 32; o > 0; o >>= 1) v += __shfl_down(v, o);
    if ((t & 63) == 0) red[t >> 6][f] = v;
  }
  if (t < 2 * kHD) {
    float v = 0.f;
    for (int k = 0; k < 8; k++) v += sums[k * 2 * kHD + t];
    tot[t] = v;
  }
  __syncthreads();
  if (t < kHD) {
    const float inv = 1.0f / (float)(kN * kB);
    float mu = tot[t] * inv;
    float var = tot[kHD + t] * inv - mu * mu;
    float a1 = g1[t] * rsqrtf(var + kEps);
    float c1 = be1[t] - mu * a1;
    float pool = (red[0][t] + red[1][t] + red[2][t] + red[3][t]) * (1.0f / kN);
    pv[t] = pool * a1 + c1;
  }
  __syncthreads();
  if (t < 64) {
    float agg = bagg[t];
#pragma unroll
    for (int f = 0; f < kHD; f++) agg = fmaf(pv[f], Wagg[f * 64 + t], agg);
    finb[(size_t)b * 1088 + t] = f2bf(agg);
  }
  if (t < 128) {
    uint4* dst = (uint4*)(finb + (size_t)b * 1088 + 64 + t * 8);
    if (flag) {
      *dst = *((const uint4*)((const u16*)obsraw + (size_t)b * 1024 + t * 8));
    } else {
      const float4* sp = (const float4*)((const float*)obsraw + (size_t)b * 1024 + t * 8);
      float4 r0 = sp[0], r1 = sp[1];
      uint4 o;
      o.x = pack_bf16(r0.x, r0.y); o.y = pack_bf16(r0.z, r0.w);
      o.z = pack_bf16(r1.x, r1.y); o.w = pack_bf16(r1.z, r1.w);
      *dst = o;
    }
  }
}

// ---------------- fused MLP: FIN -> h1 -> h2 -> logits (block = 16-row m-tile) ----------------
__global__ __launch_bounds__(256) void mlp_kernel(const u16* __restrict__ finb,
                                                  const u16* __restrict__ W1p,
                                                  const u16* __restrict__ W2p,
                                                  const u16* __restrict__ Woutp,
                                                  const float* __restrict__ bh1,
                                                  const float* __restrict__ bh2,
                                                  const float* __restrict__ bout,
                                                  const unsigned* __restrict__ xdet,
                                                  void* __restrict__ outv) {
  __shared__ __align__(16) u16 fins[16][1096];  // +8 pad: kills 16-way LDS bank conflict
  __shared__ __align__(16) u16 h1s[16][264];
  __shared__ __align__(16) u16 h2s[16][136];
  int flag = detect_flag(xdet);
  int t = threadIdx.x;
  int m0 = blockIdx.x * 16;
  // stage FIN m-tile
  for (int r = 0; r < 16; r++) {
    for (int k = t * 8; k < 1088; k += 2048)
      *(uint4*)&fins[r][k] = *(const uint4*)(finb + (size_t)(m0 + r) * 1088 + k);
  }
  __syncthreads();
  int wave = t >> 6, lane = t & 63, lo = lane & 15, quad = lane >> 4;
  // layer 1: h1[16,256]
  {
    floatx4 acc[4] = {{0.f, 0.f, 0.f, 0.f}, {0.f, 0.f, 0.f, 0.f}, {0.f, 0.f, 0.f, 0.f}, {0.f, 0.f, 0.f, 0.f}};
    for (int kb = 0; kb < 34; kb++) {
      short8 a = *(const short8*)&fins[lo][kb * 32 + quad * 8];
#pragma unroll
      for (int nt = 0; nt < 4; nt++) {
        int n0 = (wave * 4 + nt) * 16;
        short8 bf = *(const short8*)(W1p + ((size_t)(kb * 4 + quad) * 256 + n0 + lo) * 8);
        acc[nt] = __builtin_amdgcn_mfma_f32_16x16x32_bf16(a, bf, acc[nt], 0, 0, 0);
      }
    }
#pragma unroll
    for (int nt = 0; nt < 4; nt++) {
      int n0 = (wave * 4 + nt) * 16;
      float bias = bh1[n0 + lo];
#pragma unroll
      for (int r = 0; r < 4; r++) h1s[quad * 4 + r][n0 + lo] = f2bf(tanhf(acc[nt][r] + bias));
    }
  }
  __syncthreads();
  // layer 2: h2[16,128]
  {
    floatx4 acc[2] = {{0.f, 0.f, 0.f, 0.f}, {0.f, 0.f, 0.f, 0.f}};
    for (int kb = 0; kb < 8; kb++) {
      short8 a = *(const short8*)&h1s[lo][kb * 32 + quad * 8];
#pragma unroll
      for (int nt = 0; nt < 2; nt++) {
        int n0 = (wave * 2 + nt) * 16;
        short8 bf = *(const short8*)(W2p + ((size_t)(kb * 4 + quad) * 128 + n0 + lo) * 8);
        acc[nt] = __builtin_amdgcn_mfma_f32_16x16x32_bf16(a, bf, acc[nt], 0, 0, 0);
      }
    }
#pragma unroll
    for (int nt = 0; nt < 2; nt++) {
      int n0 = (wave * 2 + nt) * 16;
      float bias = bh2[n0 + lo];
#pragma unroll
      for (int r = 0; r < 4; r++) h2s[quad * 4 + r][n0 + lo] = f2bf(tanhf(acc[nt][r] + bias));
    }
  }
  __syncthreads();
  // layer 3: out[16,64]
  {
    int n0 = wave * 16;
    floatx4 acc = {0.f, 0.f, 0.f, 0.f};
    for (int kb = 0; kb < 4; kb++) {
      short8 a = *(const short8*)&h2s[lo][kb * 32 + quad * 8];
      short8 bf = *(const short8*)(Woutp + ((size_t)(kb * 4 + quad) * 64 + n0 + lo) * 8);
      acc = __builtin_amdgcn_mfma_f32_16x16x32_bf16(a, bf, acc, 0, 0, 0);
    }
    float bias = bout[n0 + lo];
    if (flag) {
      __hip_bfloat16* o = (__hip_bfloat16*)outv;
#pragma unroll
      for (int r = 0; r < 4; r++)
        o[(size_t)(m0 + quad * 4 + r) * 64 + n0 + lo] = __float2bfloat16(acc[r] + bias);
    } else {
      float* o = (float*)outv;
#pragma unroll
      for (int r = 0; r < 4; r++)
        o[(size_t)(m0 + quad * 4 + r) * 64 + n0 + lo] = acc[r] + bias;
    }
  }
}

// ---------------- launch ----------------
extern "C" void kernel_launch(void* const* d_in, const int* in_sizes, int n_in,
                              void* d_out, int out_size, void* d_ws, size_t ws_size,
                              hipStream_t stream) {
  const int* ei = (const int*)d_in[2];
  char* ws = (char*)d_ws;

  float* sums0   = (float*)(ws + 0);        // 1280
  float* sums1   = (float*)(ws + 1280);     // 1280 -> 2560
  int*   csr_off = (int*)(ws + 2816);       // 4100
  int*   csr_src = (int*)(ws + 7168);       // 36864 -> 44032
  float* convf   = (float*)(ws + 44288);    // 3072 floats -> 56576
  u16*   W1p     = (u16*)(ws + 56832);      // 557056 -> 613888
  u16*   W2p     = (u16*)(ws + 613888);     // 65536 -> 679424
  u16*   Woutp   = (u16*)(ws + 679424);     // 16384 -> 695808
  u16*   finb    = (u16*)(ws + 695808);     // 557056 -> 1252864
  float* x_f     = (float*)(ws + 1253120);  // 8388608 -> 9641728
  u16*   xlb     = (u16*)(ws + 9641728);    // 10485760 -> 20127488
  u16*   hb      = (u16*)(ws + 20127488);   // 10485760 -> 30613248
  u16*   hb2     = (u16*)(ws + 30613248);   // 10485760 -> 41099008

  const int s_din[17] = {3, 4, 5, 6, 7, 8, 9, 10, 11, 12, 13, 14, 15, 16, 18, 20, 22};
  const int s_n[17]   = {160, 160, 20, 20, 400, 400, 20, 20, 20, 20, 20, 20, 1280, 64, 256, 128, 64};
  SmallConv sc;
  float* fptr[17];
  {
    size_t co = 0;
    for (int i = 0; i < 17; i++) {
      sc.src[i] = d_in[s_din[i]];
      sc.dst[i] = convf + co;
      sc.n[i] = s_n[i];
      fptr[i] = convf + co;
      co += (size_t)s_n[i];
    }
  }
  float* Wl0_f = fptr[0],  *Wr0_f = fptr[1],  *att0_f = fptr[2], *b0_f = fptr[3];
  float* Wl1_f = fptr[4],  *Wr1_f = fptr[5],  *att1_f = fptr[6], *b1_f = fptr[7];
  float* g0_f = fptr[8],   *be0_f = fptr[9],  *g1_f = fptr[10],  *be1_f = fptr[11];
  float* Wagg_f = fptr[12], *bagg_f = fptr[13], *bh1_f = fptr[14], *bh2_f = fptr[15];
  float* bout_f = fptr[16];

  PrepArgs pa;
  pa.x = (const unsigned*)d_in[0];
  pa.ei = ei;
  pa.W1 = d_in[17]; pa.W2 = d_in[19]; pa.Wout = d_in[21];
  pa.sc = sc;
  pa.x_f = x_f;
  pa.W1p = W1p; pa.W2p = W2p; pa.Woutp = Woutp;
  pa.csr_off = csr_off; pa.csr_src = csr_src;
  pa.sums = sums0;  // zeros 640 floats = sums0+sums1

  prep_kernel<<<1182, 256, 0, stream>>>(pa);
  lin0_kernel<<<kN, 256, 0, stream>>>(x_f, Wl0_f, xlb);
  attn0_kernel<<<2 * kN, 128, 0, stream>>>(xlb, x_f, Wr0_f, att0_f, b0_f, csr_off, csr_src, hb, sums0);
  lin1_kernel<<<kN, 256, 0, stream>>>(hb, sums0, g0_f, be0_f, Wl1_f, xlb);
  attn1_kernel<<<2 * kN, 128, 0, stream>>>(xlb, hb, sums0, g0_f, be0_f, Wr1_f, att1_f, b1_f,
                                           csr_off, csr_src, hb2, sums1);
  pool_fin_kernel<<<kB, 256, 0, stream>>>(hb2, sums1, g1_f, be1_f, Wagg_f, bagg_f,
                                          d_in[1], (const unsigned*)d_in[0], finb);
  mlp_kernel<<<16, 256, 0, stream>>>(finb, W1p, W2p, Woutp, bh1_f, bh2_f, bout_f,
                                     (const unsigned*)d_in[0], d_out);
}